// Round 8
// baseline (448.979 us; speedup 1.0000x reference)
//
#include <hip/hip_runtime.h>
#include <stdint.h>

// SNN audio classifier. 512 blocks x 256 threads, 1 sample/block, T=100 in-kernel.
// Round 8: identical body to round 7; ONLY change is the occupancy attribute:
// amdgpu_waves_per_eu(2,2) pins the allocator budget to 256 VGPRs/wave so the
// ~190 live registers (fc1 weights 88 + conv2 weights 56 + conv1 pairings) fit
// WITHOUT the setup-time spill that round 7's counters exposed (WRITE_SIZE 10.9MB).

#define NB 512
#define NT 100
#define LIN 686
#define RS 71          // spool2 row stride in v2f; cols 0,69,70 are zero pads

typedef float v2f __attribute__((ext_vector_type(2)));

__device__ __forceinline__ v2f pkfma(v2f a, v2f b, v2f c) {
    v2f d;
    asm("v_pk_fma_f32 %0, %1, %2, %3" : "=v"(d) : "v"(a), "v"(b), "v"(c));
    return d;
}

__device__ __forceinline__ float dpp_add8(float x) {   // sum over 8-lane groups
    int t;
    t = __builtin_amdgcn_mov_dpp(__float_as_int(x), 0x141, 0xf, 0xf, true); // row_half_mirror
    x += __int_as_float(t);
    t = __builtin_amdgcn_mov_dpp(__float_as_int(x), 0x1B, 0xf, 0xf, true);  // quad_perm [3,2,1,0]
    x += __int_as_float(t);
    t = __builtin_amdgcn_mov_dpp(__float_as_int(x), 0xB1, 0xf, 0xf, true);  // quad_perm [1,0,3,2]
    x += __int_as_float(t);
    return x;
}

__device__ __forceinline__ float red32(float x) {      // sum over 32-lane groups
    int t;
    t = __builtin_amdgcn_mov_dpp(__float_as_int(x), 0xB1, 0xf, 0xf, true);  // xor1
    x += __int_as_float(t);
    t = __builtin_amdgcn_mov_dpp(__float_as_int(x), 0x4E, 0xf, 0xf, true);  // xor2
    x += __int_as_float(t);
    t = __builtin_amdgcn_ds_swizzle(__float_as_int(x), 0x101F);             // xor4
    x += __int_as_float(t);
    t = __builtin_amdgcn_ds_swizzle(__float_as_int(x), 0x201F);             // xor8
    x += __int_as_float(t);
    t = __builtin_amdgcn_ds_swizzle(__float_as_int(x), 0x401F);             // xor16
    x += __int_as_float(t);
    return x;
}

__global__
__attribute__((amdgpu_flat_work_group_size(256, 256)))
__attribute__((amdgpu_waves_per_eu(2, 2)))
void snn_all(
    const float* __restrict__ x,
    const float* __restrict__ w1, const float* __restrict__ b1,
    const float* __restrict__ w2, const float* __restrict__ b2,
    const float* __restrict__ wf1, const float* __restrict__ bf1,
    const float* __restrict__ wf2, const float* __restrict__ bf2,
    float* __restrict__ out)
{
    __shared__ __align__(16) float sx[LIN + 2];
    __shared__ __align__(16) float spool2f[8 * RS * 2];   // v2f-interleaved pooled spikes
    __shared__ unsigned long long sbits[4][3];
    __shared__ __align__(16) float sspk3[32];

    const int t2   = threadIdx.x;
    const int b    = blockIdx.x;
    const int lane = t2 & 63;
    const int wv   = t2 >> 6;          // wave 0..3

    // ---- phase A setup: conv1. thread = (ca = t2&15, pg = t2>>4) ----
    const int ca = t2 & 15;
    const int pg = t2 >> 4;
    float wA[13];
    #pragma unroll
    for (int k = 0; k < 13; ++k) wA[k] = w1[ca * 13 + k];
    v2f we0 = {wA[0], wA[1]}, we1 = {wA[2], wA[3]}, we2 = {wA[4], wA[5]},
        we3 = {wA[6], wA[7]}, we4 = {wA[8], wA[9]}, we5 = {wA[10], wA[11]};
    v2f wo0 = {wA[1], wA[2]}, wo1 = {wA[3], wA[4]}, wo2 = {wA[5], wA[6]},
        wo3 = {wA[7], wA[8]}, wo4 = {wA[9], wA[10]}, wo5 = {wA[11], wA[12]};
    const float wA0s = wA[0], wA12s = wA[12];
    const float bA = b1[ca];
    float m1a[5], m1b[5];
    #pragma unroll
    for (int j = 0; j < 5; ++j) { m1a[j] = 0.f; m1b[j] = 0.f; }

    // ---- phase B setup: conv2. lane = (X = l>>3 -> cg,og ; ip = l&7) ----
    const int ip = lane & 7;           // row-pair (conv1 channel pair 2ip,2ip+1)
    const int X  = lane >> 3;
    const int og = X & 3;              // output phase: o = og + 4*om
    const int cg = X >> 2;             // channel-quartet within wave's octet
    const int ccq = ip & 3;            // owner's channel within quartet
    const int chO = wv * 8 + cg * 4 + ccq;   // owned channel
    // weights: wp[q][k] = { w2[ch][2ip][k], w2[ch][2ip+1][k] }, ch = wv*8+cg*4+q
    v2f wp0[7], wp1[7], wp2[7], wp3[7];
    #pragma unroll
    for (int k = 0; k < 7; ++k) {
        int base0 = (wv * 8 + cg * 4 + 0) * 112 + 14 * ip + k;
        int base1 = (wv * 8 + cg * 4 + 1) * 112 + 14 * ip + k;
        int base2 = (wv * 8 + cg * 4 + 2) * 112 + 14 * ip + k;
        int base3 = (wv * 8 + cg * 4 + 3) * 112 + 14 * ip + k;
        wp0[k].x = w2[base0]; wp0[k].y = w2[base0 + 7];
        wp1[k].x = w2[base1]; wp1[k].y = w2[base1 + 7];
        wp2[k].x = w2[base2]; wp2[k].y = w2[base2 + 7];
        wp3[k].x = w2[base3]; wp3[k].y = w2[base3 + 7];
    }
    const float bB = b2[chO];
    float m2r0 = 0.f, m2r1 = 0.f, m2r2 = 0.f;

    // ---- phase C setup: fc1. lane = (jb = 4 outputs, s_ = channel) ----
    const int gg = (t2 >> 5) & 1;
    const int s_ = t2 & 31;
    const int jb = wv * 8 + gg * 4;
    v2f wj0[11], wj1[11], wj2[11], wj3[11];
    #pragma unroll
    for (int i = 0; i < 11; ++i) {
        wj0[i].x = wf1[(jb + 0) * 704 + s_ * 22 + 2 * i];
        wj0[i].y = wf1[(jb + 0) * 704 + s_ * 22 + 2 * i + 1];
        wj1[i].x = wf1[(jb + 1) * 704 + s_ * 22 + 2 * i];
        wj1[i].y = wf1[(jb + 1) * 704 + s_ * 22 + 2 * i + 1];
        wj2[i].x = wf1[(jb + 2) * 704 + s_ * 22 + 2 * i];
        wj2[i].y = wf1[(jb + 2) * 704 + s_ * 22 + 2 * i + 1];
        wj3[i].x = wf1[(jb + 3) * 704 + s_ * 22 + 2 * i];
        wj3[i].y = wf1[(jb + 3) * 704 + s_ * 22 + 2 * i + 1];
    }
    float bC0 = bf1[jb], bC1 = bf1[jb + 1], bC2 = bf1[jb + 2], bC3 = bf1[jb + 3];
    float m30 = 0.f, m31 = 0.f, m32 = 0.f, m33 = 0.f;
    const int cbsh = ((s_ >> 2) & 1) * 32 + (s_ & 3);   // runtime bit base

    // ---- phase D setup: fc2 ----
    float wD = 0.f, bD = 0.f;
    if (t2 < 64) {
        wD = wf2[(t2 >> 5) * 32 + (t2 & 31)];
        if ((t2 & 31) == 0) bD = bf2[t2 >> 5];
    }
    float m4 = 0.f, cnt = 0.f;

    // ---- init LDS ----
    for (int i = t2; i < 8 * RS * 2; i += 256) spool2f[i] = 0.f;  // pads stay 0
    const float* xb = x + (size_t)b * NT * LIN;
    if (t2 == 0) { sx[0] = 0.f; sx[LIN + 1] = 0.f; }
    sx[1 + t2]       = xb[t2];
    sx[1 + t2 + 256] = xb[t2 + 256];
    if (t2 < LIN - 512) sx[1 + t2 + 512] = xb[t2 + 512];
    __syncthreads();

    const v2f* spool2v = reinterpret_cast<const v2f*>(spool2f);
    const v2f* wb = spool2v + ip * RS + 3 * og;   // per-lane window base (static offsets from here)

// ===== phase A: conv1 (k13,s5,p1) + LIF1 + maxpool2; window = sx[10p .. 10p+17] =====
#define A_J(j) { \
    const int p_ = ((j) == 4) ? (64 + pg) : (pg + 16 * (j)); \
    if ((j) < 4 || pg < 4) { \
        const v2f* qv_ = reinterpret_cast<const v2f*>(sx + 10 * p_); \
        v2f q0_ = qv_[0], q1_ = qv_[1], q2_ = qv_[2], q3_ = qv_[3], q4_ = qv_[4], \
            q5_ = qv_[5], q6_ = qv_[6], q7_ = qv_[7], q8_ = qv_[8]; \
        v2f va_ = {0.f, 0.f}, vb_ = {0.f, 0.f}; \
        va_ = pkfma(we0, q0_, va_); va_ = pkfma(we1, q1_, va_); \
        va_ = pkfma(we2, q2_, va_); va_ = pkfma(we3, q3_, va_); \
        va_ = pkfma(we4, q4_, va_); va_ = pkfma(we5, q5_, va_); \
        vb_ = pkfma(wo0, q3_, vb_); vb_ = pkfma(wo1, q4_, vb_); \
        vb_ = pkfma(wo2, q5_, vb_); vb_ = pkfma(wo3, q6_, vb_); \
        vb_ = pkfma(wo4, q7_, vb_); vb_ = pkfma(wo5, q8_, vb_); \
        float a0_ = (va_.x + va_.y) + wA12s * q6_.x; \
        float a1_ = (vb_.x + vb_.y) + wA0s * q2_.y; \
        float m0_ = m1a[(j)], mm_ = m1b[(j)]; \
        float r0_ = (m0_ > 1.f) ? 1.f : 0.f; \
        float r1_ = (mm_ > 1.f) ? 1.f : 0.f; \
        m0_ = 0.9f * m0_ + (a0_ + bA) - r0_; \
        mm_ = 0.9f * mm_ + (a1_ + bA) - r1_; \
        m1a[(j)] = m0_; m1b[(j)] = mm_; \
        spool2f[((ca >> 1) * RS + 1 + p_) * 2 + (ca & 1)] = \
            (m0_ > 1.f || mm_ > 1.f) ? 1.f : 0.f; \
    } }

// ===== phase B window: o = og + 4*om; 7 v2f taps, 4 channels, dpp reduce, owner LIF =====
#define B_WIN(om, MSLOT, SPK) { \
    v2f t0_ = wb[(om) * 12 + 0], t1_ = wb[(om) * 12 + 1], t2v_ = wb[(om) * 12 + 2], \
        t3_ = wb[(om) * 12 + 3], t4_ = wb[(om) * 12 + 4], t5_ = wb[(om) * 12 + 5], \
        t6_ = wb[(om) * 12 + 6]; \
    v2f a0_ = {0.f, 0.f}, a1_ = {0.f, 0.f}, a2_ = {0.f, 0.f}, a3_ = {0.f, 0.f}; \
    a0_ = pkfma(wp0[0], t0_, a0_); a1_ = pkfma(wp1[0], t0_, a1_); \
    a2_ = pkfma(wp2[0], t0_, a2_); a3_ = pkfma(wp3[0], t0_, a3_); \
    a0_ = pkfma(wp0[1], t1_, a0_); a1_ = pkfma(wp1[1], t1_, a1_); \
    a2_ = pkfma(wp2[1], t1_, a2_); a3_ = pkfma(wp3[1], t1_, a3_); \
    a0_ = pkfma(wp0[2], t2v_, a0_); a1_ = pkfma(wp1[2], t2v_, a1_); \
    a2_ = pkfma(wp2[2], t2v_, a2_); a3_ = pkfma(wp3[2], t2v_, a3_); \
    a0_ = pkfma(wp0[3], t3_, a0_); a1_ = pkfma(wp1[3], t3_, a1_); \
    a2_ = pkfma(wp2[3], t3_, a2_); a3_ = pkfma(wp3[3], t3_, a3_); \
    a0_ = pkfma(wp0[4], t4_, a0_); a1_ = pkfma(wp1[4], t4_, a1_); \
    a2_ = pkfma(wp2[4], t4_, a2_); a3_ = pkfma(wp3[4], t4_, a3_); \
    a0_ = pkfma(wp0[5], t5_, a0_); a1_ = pkfma(wp1[5], t5_, a1_); \
    a2_ = pkfma(wp2[5], t5_, a2_); a3_ = pkfma(wp3[5], t5_, a3_); \
    a0_ = pkfma(wp0[6], t6_, a0_); a1_ = pkfma(wp1[6], t6_, a1_); \
    a2_ = pkfma(wp2[6], t6_, a2_); a3_ = pkfma(wp3[6], t6_, a3_); \
    float s0_ = dpp_add8(a0_.x + a0_.y); \
    float s1_ = dpp_add8(a1_.x + a1_.y); \
    float s2_ = dpp_add8(a2_.x + a2_.y); \
    float s3_ = dpp_add8(a3_.x + a3_.y); \
    float sc_ = (ccq == 0) ? s0_ : ((ccq == 1) ? s1_ : ((ccq == 2) ? s2_ : s3_)); \
    if ((ip >> 2) == ((om) & 1)) { \
        float mm_ = MSLOT; \
        float rr_ = (mm_ > 1.f) ? 1.f : 0.f; \
        mm_ = 0.9f * mm_ + (sc_ + bB) - rr_; \
        MSLOT = mm_; \
        SPK = (mm_ > 1.f) ? 1.f : 0.f; \
    } }

    for (int t = 0; t < NT; ++t) {
        // ===== phase A =====
        A_J(0) A_J(1) A_J(2) A_J(3) A_J(4)
        __syncthreads();   // bar1: spool2 ready; sx free to overwrite

        // ===== prefetch x(t+1) =====
        float xp0 = 0.f, xp1 = 0.f, xp2 = 0.f;
        if (t + 1 < NT) {
            const float* xt = xb + (size_t)(t + 1) * LIN;
            xp0 = xt[t2];
            xp1 = xt[t2 + 256];
            if (t2 < LIN - 512) xp2 = xt[t2 + 512];
        }

        // ===== phase B: conv2 + LIF2 (float windows, 4ch/lane) =====
        float spk0 = 0.f, spk1 = 0.f, spk2 = 0.f;
        B_WIN(0, m2r0, spk0)
        B_WIN(1, m2r0, spk0)
        B_WIN(2, m2r1, spk1)
        B_WIN(3, m2r1, spk1)
        B_WIN(4, m2r2, spk2)
        if (og < 2) { B_WIN(5, m2r2, spk2) }

        // publish spikes as bits
        {
            unsigned long long bal0 = __ballot(spk0 > 0.5f);
            unsigned long long bal1 = __ballot(spk1 > 0.5f);
            unsigned long long bal2 = __ballot(spk2 > 0.5f);
            if (lane == 0) {
                sbits[wv][0] = bal0;
                sbits[wv][1] = bal1;
                sbits[wv][2] = bal2;
            }
        }

        // write x(t+1) (readers of sx are behind bar2+bar3)
        if (t + 1 < NT) {
            sx[1 + t2]       = xp0;
            sx[1 + t2 + 256] = xp1;
            if (t2 < LIN - 512) sx[1 + t2 + 512] = xp2;
        }
        __syncthreads();   // bar2: sbits ready

        // ===== phase C: fc1 (704->32) + LIF3, register weights, static bit map =====
        {
            unsigned long long M0 = sbits[s_ >> 3][0];
            unsigned long long M1 = sbits[s_ >> 3][1];
            unsigned long long M2 = sbits[s_ >> 3][2];
            uint32_t W0 = (uint32_t)(M0 >> cbsh);
            uint32_t W1 = (uint32_t)(M1 >> cbsh);
            uint32_t W2 = (uint32_t)(M2 >> cbsh);

            // f[o] = bit (o&3)*8 + ((o>>2)&1)*4 of W[o>>3]
            float f[22];
            #pragma unroll
            for (int o = 0; o < 22; ++o) {
                uint32_t w = (o < 8) ? W0 : ((o < 16) ? W1 : W2);
                f[o] = (float)((w >> ((o & 3) * 8 + ((o >> 2) & 1) * 4)) & 1u);
            }

            v2f fp[11];
            #pragma unroll
            for (int i = 0; i < 11; ++i) fp[i] = (v2f){f[2 * i], f[2 * i + 1]};

            v2f a0v = {0.f, 0.f}, a1v = {0.f, 0.f}, a2v = {0.f, 0.f}, a3v = {0.f, 0.f};
            #pragma unroll
            for (int i = 0; i < 11; ++i) {
                a0v = pkfma(wj0[i], fp[i], a0v);
                a1v = pkfma(wj1[i], fp[i], a1v);
                a2v = pkfma(wj2[i], fp[i], a2v);
                a3v = pkfma(wj3[i], fp[i], a3v);
            }
            float a0 = red32(a0v.x + a0v.y);
            float a1 = red32(a1v.x + a1v.y);
            float a2 = red32(a2v.x + a2v.y);
            float a3 = red32(a3v.x + a3v.y);

            float r0 = (m30 > 1.f) ? 1.f : 0.f; m30 = 0.9f * m30 + (a0 + bC0) - r0;
            float r1 = (m31 > 1.f) ? 1.f : 0.f; m31 = 0.9f * m31 + (a1 + bC1) - r1;
            float r2 = (m32 > 1.f) ? 1.f : 0.f; m32 = 0.9f * m32 + (a2 + bC2) - r2;
            float r3 = (m33 > 1.f) ? 1.f : 0.f; m33 = 0.9f * m33 + (a3 + bC3) - r3;
            if (s_ == 0) {
                float4 st;
                st.x = (m30 > 1.f) ? 1.f : 0.f;
                st.y = (m31 > 1.f) ? 1.f : 0.f;
                st.z = (m32 > 1.f) ? 1.f : 0.f;
                st.w = (m33 > 1.f) ? 1.f : 0.f;
                *reinterpret_cast<float4*>(&sspk3[jb]) = st;
            }
        }
        __syncthreads();   // bar3: sspk3 ready

        // ===== phase D: fc2 (32->2) + LIF4 + count =====
        if (t2 < 64) {
            float v = sspk3[t2 & 31] * wD;
            v += __shfl_xor(v, 16, 32);
            v += __shfl_xor(v, 8, 32);
            v += __shfl_xor(v, 4, 32);
            v += __shfl_xor(v, 2, 32);
            v += __shfl_xor(v, 1, 32);
            if ((t2 & 31) == 0) {
                float rr = (m4 > 1.f) ? 1.f : 0.f;
                m4 = 0.9f * m4 + (v + bD) - rr;
                if (m4 > 1.f) cnt += 1.f;
            }
        }
        // no barrier: next writer of sspk3 (phase C of t+1) is behind bar1+bar2
    }

    if (t2 == 0)  out[b * 2 + 0] = cnt;
    if (t2 == 32) out[b * 2 + 1] = cnt;
}

extern "C" void kernel_launch(void* const* d_in, const int* in_sizes, int n_in,
                              void* d_out, int out_size, void* d_ws, size_t ws_size,
                              hipStream_t stream) {
    const float* x   = (const float*)d_in[0];
    const float* w1  = (const float*)d_in[1];
    const float* b1  = (const float*)d_in[2];
    const float* w2  = (const float*)d_in[3];
    const float* b2  = (const float*)d_in[4];
    const float* wf1 = (const float*)d_in[5];
    const float* bf1 = (const float*)d_in[6];
    const float* wf2 = (const float*)d_in[7];
    const float* bf2 = (const float*)d_in[8];
    float* out = (float*)d_out;

    snn_all<<<NB, 256, 0, stream>>>(x, w1, b1, w2, b2, wf1, bf1, wf2, bf2, out);
}

// Round 9
// 404.739 us; speedup vs baseline: 1.1093x; 1.1093x over previous
//
#include <hip/hip_runtime.h>
#include <stdint.h>

// SNN audio classifier. 256 blocks x 512 threads, 2 samples/block (h = tid>>8),
// T=100 in-kernel. Round 9: fc1 weights moved to LDS in a conflict-free
// [wave][i][lane] float4 layout (shared by both halves); all arithmetic is
// bit-identical to round 8. Register demand ~145 (was ~200 -> scratch spills).

#define NB 512
#define NT 100
#define LIN 686
#define RS 71          // spool2 row stride in v2f; cols 0,69,70 are zero pads

typedef float v2f __attribute__((ext_vector_type(2)));

__device__ __forceinline__ v2f pkfma(v2f a, v2f b, v2f c) {
    v2f d;
    asm("v_pk_fma_f32 %0, %1, %2, %3" : "=v"(d) : "v"(a), "v"(b), "v"(c));
    return d;
}

__device__ __forceinline__ float dpp_add8(float x) {   // sum over 8-lane groups
    int t;
    t = __builtin_amdgcn_mov_dpp(__float_as_int(x), 0x141, 0xf, 0xf, true); // row_half_mirror
    x += __int_as_float(t);
    t = __builtin_amdgcn_mov_dpp(__float_as_int(x), 0x1B, 0xf, 0xf, true);  // quad_perm [3,2,1,0]
    x += __int_as_float(t);
    t = __builtin_amdgcn_mov_dpp(__float_as_int(x), 0xB1, 0xf, 0xf, true);  // quad_perm [1,0,3,2]
    x += __int_as_float(t);
    return x;
}

__device__ __forceinline__ float red32(float x) {      // sum over 32-lane groups
    int t;
    t = __builtin_amdgcn_mov_dpp(__float_as_int(x), 0xB1, 0xf, 0xf, true);  // xor1
    x += __int_as_float(t);
    t = __builtin_amdgcn_mov_dpp(__float_as_int(x), 0x4E, 0xf, 0xf, true);  // xor2
    x += __int_as_float(t);
    t = __builtin_amdgcn_ds_swizzle(__float_as_int(x), 0x101F);             // xor4
    x += __int_as_float(t);
    t = __builtin_amdgcn_ds_swizzle(__float_as_int(x), 0x201F);             // xor8
    x += __int_as_float(t);
    t = __builtin_amdgcn_ds_swizzle(__float_as_int(x), 0x401F);             // xor16
    x += __int_as_float(t);
    return x;
}

__global__
__attribute__((amdgpu_flat_work_group_size(512, 512)))
__attribute__((amdgpu_waves_per_eu(1, 2)))
void snn_all(
    const float* __restrict__ x,
    const float* __restrict__ w1, const float* __restrict__ b1,
    const float* __restrict__ w2, const float* __restrict__ b2,
    const float* __restrict__ wf1, const float* __restrict__ bf1,
    const float* __restrict__ wf2, const float* __restrict__ bf2,
    float* __restrict__ out)
{
    // fc1 weights, reordered: f4[(wv*22 + i)*64 + lane]; i<11 -> {wj0p,wj1p},
    // i>=11 -> {wj2p,wj3p} for pair index i-11. Shared by both halves.
    __shared__ __align__(16) float swf1r[5632 * 4];            // 90112 B
    __shared__ __align__(16) float sx[2][LIN + 2];
    __shared__ __align__(16) float spool2f[2][8 * RS * 2];
    __shared__ unsigned long long sbits[2][4][3];
    __shared__ __align__(16) float sspk3[2][32];

    const int tid  = threadIdx.x;
    const int h    = tid >> 8;
    const int t2   = tid & 255;
    const int b    = blockIdx.x * 2 + h;
    const int lane = t2 & 63;
    const int wv   = t2 >> 6;          // wave within the half: 0..3

    float* sxh    = sx[h];
    float* spoolh = spool2f[h];
    unsigned long long (*sbh)[3] = sbits[h];
    float* sspk3h = sspk3[h];

    // ---------------- one-time init: reorder wf1 into LDS ----------------
    for (int d = tid; d < 5632; d += 512) {
        int wvd = d / 1408;            // 1408 = 22*64
        int r   = d - wvd * 1408;
        int i   = r >> 6;
        int l   = r & 63;
        int gg  = (l >> 5) & 1;
        int s   = l & 31;
        int jb0 = wvd * 8 + gg * 4;
        int ii  = (i < 11) ? i : (i - 11);
        int j0  = (i < 11) ? jb0 : (jb0 + 2);
        float4 v;
        v.x = wf1[(j0 + 0) * 704 + s * 22 + 2 * ii];
        v.y = wf1[(j0 + 0) * 704 + s * 22 + 2 * ii + 1];
        v.z = wf1[(j0 + 1) * 704 + s * 22 + 2 * ii];
        v.w = wf1[(j0 + 1) * 704 + s * 22 + 2 * ii + 1];
        reinterpret_cast<float4*>(swf1r)[d] = v;
    }

    // ---- phase A setup: conv1. thread = (ca = t2&15, pg = t2>>4) ----
    const int ca = t2 & 15;
    const int pg = t2 >> 4;
    float wA[13];
    #pragma unroll
    for (int k = 0; k < 13; ++k) wA[k] = w1[ca * 13 + k];
    v2f we0 = {wA[0], wA[1]}, we1 = {wA[2], wA[3]}, we2 = {wA[4], wA[5]},
        we3 = {wA[6], wA[7]}, we4 = {wA[8], wA[9]}, we5 = {wA[10], wA[11]};
    v2f wo0 = {wA[1], wA[2]}, wo1 = {wA[3], wA[4]}, wo2 = {wA[5], wA[6]},
        wo3 = {wA[7], wA[8]}, wo4 = {wA[9], wA[10]}, wo5 = {wA[11], wA[12]};
    const float wA0s = wA[0], wA12s = wA[12];
    const float bA = b1[ca];
    float m1a[5], m1b[5];
    #pragma unroll
    for (int j = 0; j < 5; ++j) { m1a[j] = 0.f; m1b[j] = 0.f; }

    // ---- phase B setup: conv2. lane = (X = l>>3 -> cg,og ; ip = l&7) ----
    const int ip = lane & 7;           // row-pair (conv1 channel pair 2ip,2ip+1)
    const int X  = lane >> 3;
    const int og = X & 3;              // output phase: o = og + 4*om
    const int cg = X >> 2;             // channel-quartet within wave's octet
    const int ccq = ip & 3;            // owner's channel within quartet
    const int chO = wv * 8 + cg * 4 + ccq;   // owned channel
    v2f wp0[7], wp1[7], wp2[7], wp3[7];
    #pragma unroll
    for (int k = 0; k < 7; ++k) {
        int base0 = (wv * 8 + cg * 4 + 0) * 112 + 14 * ip + k;
        int base1 = (wv * 8 + cg * 4 + 1) * 112 + 14 * ip + k;
        int base2 = (wv * 8 + cg * 4 + 2) * 112 + 14 * ip + k;
        int base3 = (wv * 8 + cg * 4 + 3) * 112 + 14 * ip + k;
        wp0[k].x = w2[base0]; wp0[k].y = w2[base0 + 7];
        wp1[k].x = w2[base1]; wp1[k].y = w2[base1 + 7];
        wp2[k].x = w2[base2]; wp2[k].y = w2[base2 + 7];
        wp3[k].x = w2[base3]; wp3[k].y = w2[base3 + 7];
    }
    const float bB = b2[chO];
    float m2r0 = 0.f, m2r1 = 0.f, m2r2 = 0.f;

    // ---- phase C setup: fc1. lane = (jb = 4 outputs, s_ = channel) ----
    const int gg = (t2 >> 5) & 1;
    const int s_ = t2 & 31;
    const int jb = wv * 8 + gg * 4;
    float bC0 = bf1[jb], bC1 = bf1[jb + 1], bC2 = bf1[jb + 2], bC3 = bf1[jb + 3];
    float m30 = 0.f, m31 = 0.f, m32 = 0.f, m33 = 0.f;
    const int cbsh = ((s_ >> 2) & 1) * 32 + (s_ & 3);   // runtime bit base

    // ---- phase D setup: fc2 ----
    float wD = 0.f, bD = 0.f;
    if (t2 < 64) {
        wD = wf2[(t2 >> 5) * 32 + (t2 & 31)];
        if ((t2 & 31) == 0) bD = bf2[t2 >> 5];
    }
    float m4 = 0.f, cnt = 0.f;

    // ---- init LDS (per half) ----
    for (int i = t2; i < 8 * RS * 2; i += 256) spoolh[i] = 0.f;  // pads stay 0
    const float* xb = x + (size_t)b * NT * LIN;
    if (t2 == 0) { sxh[0] = 0.f; sxh[LIN + 1] = 0.f; }
    sxh[1 + t2]       = xb[t2];
    sxh[1 + t2 + 256] = xb[t2 + 256];
    if (t2 < LIN - 512) sxh[1 + t2 + 512] = xb[t2 + 512];
    __syncthreads();

    const v2f* spool2v = reinterpret_cast<const v2f*>(spoolh);
    const v2f* wb = spool2v + ip * RS + 3 * og;   // per-lane window base
    const float4* swfv = reinterpret_cast<const float4*>(swf1r);
    const float4* wrow = swfv + (wv * 22) * 64 + lane;

// ===== phase A: conv1 (k13,s5,p1) + LIF1 + maxpool2; window = sx[10p .. 10p+17] =====
#define A_J(j) { \
    const int p_ = ((j) == 4) ? (64 + pg) : (pg + 16 * (j)); \
    if ((j) < 4 || pg < 4) { \
        const v2f* qv_ = reinterpret_cast<const v2f*>(sxh + 10 * p_); \
        v2f q0_ = qv_[0], q1_ = qv_[1], q2_ = qv_[2], q3_ = qv_[3], q4_ = qv_[4], \
            q5_ = qv_[5], q6_ = qv_[6], q7_ = qv_[7], q8_ = qv_[8]; \
        v2f va_ = {0.f, 0.f}, vb_ = {0.f, 0.f}; \
        va_ = pkfma(we0, q0_, va_); va_ = pkfma(we1, q1_, va_); \
        va_ = pkfma(we2, q2_, va_); va_ = pkfma(we3, q3_, va_); \
        va_ = pkfma(we4, q4_, va_); va_ = pkfma(we5, q5_, va_); \
        vb_ = pkfma(wo0, q3_, vb_); vb_ = pkfma(wo1, q4_, vb_); \
        vb_ = pkfma(wo2, q5_, vb_); vb_ = pkfma(wo3, q6_, vb_); \
        vb_ = pkfma(wo4, q7_, vb_); vb_ = pkfma(wo5, q8_, vb_); \
        float a0_ = (va_.x + va_.y) + wA12s * q6_.x; \
        float a1_ = (vb_.x + vb_.y) + wA0s * q2_.y; \
        float m0_ = m1a[(j)], mm_ = m1b[(j)]; \
        float r0_ = (m0_ > 1.f) ? 1.f : 0.f; \
        float r1_ = (mm_ > 1.f) ? 1.f : 0.f; \
        m0_ = 0.9f * m0_ + (a0_ + bA) - r0_; \
        mm_ = 0.9f * mm_ + (a1_ + bA) - r1_; \
        m1a[(j)] = m0_; m1b[(j)] = mm_; \
        spoolh[((ca >> 1) * RS + 1 + p_) * 2 + (ca & 1)] = \
            (m0_ > 1.f || mm_ > 1.f) ? 1.f : 0.f; \
    } }

// ===== phase B window: o = og + 4*om; 7 v2f taps, 4 channels, dpp reduce, owner LIF =====
#define B_WIN(om, MSLOT, SPK) { \
    v2f t0_ = wb[(om) * 12 + 0], t1_ = wb[(om) * 12 + 1], t2v_ = wb[(om) * 12 + 2], \
        t3_ = wb[(om) * 12 + 3], t4_ = wb[(om) * 12 + 4], t5_ = wb[(om) * 12 + 5], \
        t6_ = wb[(om) * 12 + 6]; \
    v2f a0_ = {0.f, 0.f}, a1_ = {0.f, 0.f}, a2_ = {0.f, 0.f}, a3_ = {0.f, 0.f}; \
    a0_ = pkfma(wp0[0], t0_, a0_); a1_ = pkfma(wp1[0], t0_, a1_); \
    a2_ = pkfma(wp2[0], t0_, a2_); a3_ = pkfma(wp3[0], t0_, a3_); \
    a0_ = pkfma(wp0[1], t1_, a0_); a1_ = pkfma(wp1[1], t1_, a1_); \
    a2_ = pkfma(wp2[1], t1_, a2_); a3_ = pkfma(wp3[1], t1_, a3_); \
    a0_ = pkfma(wp0[2], t2v_, a0_); a1_ = pkfma(wp1[2], t2v_, a1_); \
    a2_ = pkfma(wp2[2], t2v_, a2_); a3_ = pkfma(wp3[2], t2v_, a3_); \
    a0_ = pkfma(wp0[3], t3_, a0_); a1_ = pkfma(wp1[3], t3_, a1_); \
    a2_ = pkfma(wp2[3], t3_, a2_); a3_ = pkfma(wp3[3], t3_, a3_); \
    a0_ = pkfma(wp0[4], t4_, a0_); a1_ = pkfma(wp1[4], t4_, a1_); \
    a2_ = pkfma(wp2[4], t4_, a2_); a3_ = pkfma(wp3[4], t4_, a3_); \
    a0_ = pkfma(wp0[5], t5_, a0_); a1_ = pkfma(wp1[5], t5_, a1_); \
    a2_ = pkfma(wp2[5], t5_, a2_); a3_ = pkfma(wp3[5], t5_, a3_); \
    a0_ = pkfma(wp0[6], t6_, a0_); a1_ = pkfma(wp1[6], t6_, a1_); \
    a2_ = pkfma(wp2[6], t6_, a2_); a3_ = pkfma(wp3[6], t6_, a3_); \
    float s0_ = dpp_add8(a0_.x + a0_.y); \
    float s1_ = dpp_add8(a1_.x + a1_.y); \
    float s2_ = dpp_add8(a2_.x + a2_.y); \
    float s3_ = dpp_add8(a3_.x + a3_.y); \
    float sc_ = (ccq == 0) ? s0_ : ((ccq == 1) ? s1_ : ((ccq == 2) ? s2_ : s3_)); \
    if ((ip >> 2) == ((om) & 1)) { \
        float mm_ = MSLOT; \
        float rr_ = (mm_ > 1.f) ? 1.f : 0.f; \
        mm_ = 0.9f * mm_ + (sc_ + bB) - rr_; \
        MSLOT = mm_; \
        SPK = (mm_ > 1.f) ? 1.f : 0.f; \
    } }

    for (int t = 0; t < NT; ++t) {
        // ===== phase A =====
        A_J(0) A_J(1) A_J(2) A_J(3) A_J(4)
        __syncthreads();   // bar1: spool2 ready; sx free to overwrite

        // ===== prefetch x(t+1) =====
        float xp0 = 0.f, xp1 = 0.f, xp2 = 0.f;
        if (t + 1 < NT) {
            const float* xt = xb + (size_t)(t + 1) * LIN;
            xp0 = xt[t2];
            xp1 = xt[t2 + 256];
            if (t2 < LIN - 512) xp2 = xt[t2 + 512];
        }

        // ===== phase B: conv2 + LIF2 (float windows, 4ch/lane) =====
        float spk0 = 0.f, spk1 = 0.f, spk2 = 0.f;
        B_WIN(0, m2r0, spk0)
        B_WIN(1, m2r0, spk0)
        B_WIN(2, m2r1, spk1)
        B_WIN(3, m2r1, spk1)
        B_WIN(4, m2r2, spk2)
        if (og < 2) { B_WIN(5, m2r2, spk2) }

        // publish spikes as bits
        {
            unsigned long long bal0 = __ballot(spk0 > 0.5f);
            unsigned long long bal1 = __ballot(spk1 > 0.5f);
            unsigned long long bal2 = __ballot(spk2 > 0.5f);
            if (lane == 0) {
                sbh[wv][0] = bal0;
                sbh[wv][1] = bal1;
                sbh[wv][2] = bal2;
            }
        }

        // write x(t+1) (readers of sx are behind bar2+bar3)
        if (t + 1 < NT) {
            sxh[1 + t2]       = xp0;
            sxh[1 + t2 + 256] = xp1;
            if (t2 < LIN - 512) sxh[1 + t2 + 512] = xp2;
        }
        __syncthreads();   // bar2: sbits ready

        // ===== phase C: fc1 (704->32) + LIF3, LDS weights, static bit map =====
        {
            unsigned long long M0 = sbh[s_ >> 3][0];
            unsigned long long M1 = sbh[s_ >> 3][1];
            unsigned long long M2 = sbh[s_ >> 3][2];
            uint32_t W0 = (uint32_t)(M0 >> cbsh);
            uint32_t W1 = (uint32_t)(M1 >> cbsh);
            uint32_t W2 = (uint32_t)(M2 >> cbsh);

            v2f a0v = {0.f, 0.f}, a1v = {0.f, 0.f}, a2v = {0.f, 0.f}, a3v = {0.f, 0.f};
            #pragma unroll
            for (int i = 0; i < 11; ++i) {
                const int o0 = 2 * i, o1 = 2 * i + 1;
                uint32_t wl0 = (o0 < 8) ? W0 : ((o0 < 16) ? W1 : W2);
                uint32_t wl1 = (o1 < 8) ? W0 : ((o1 < 16) ? W1 : W2);
                v2f fpi;
                fpi.x = (float)((wl0 >> ((o0 & 3) * 8 + ((o0 >> 2) & 1) * 4)) & 1u);
                fpi.y = (float)((wl1 >> ((o1 & 3) * 8 + ((o1 >> 2) & 1) * 4)) & 1u);
                float4 wa  = wrow[i * 64];          // {wj0p, wj1p}
                float4 wb4 = wrow[(11 + i) * 64];   // {wj2p, wj3p}
                a0v = pkfma((v2f){wa.x,  wa.y},  fpi, a0v);
                a1v = pkfma((v2f){wa.z,  wa.w},  fpi, a1v);
                a2v = pkfma((v2f){wb4.x, wb4.y}, fpi, a2v);
                a3v = pkfma((v2f){wb4.z, wb4.w}, fpi, a3v);
            }
            float a0 = red32(a0v.x + a0v.y);
            float a1 = red32(a1v.x + a1v.y);
            float a2 = red32(a2v.x + a2v.y);
            float a3 = red32(a3v.x + a3v.y);

            float r0 = (m30 > 1.f) ? 1.f : 0.f; m30 = 0.9f * m30 + (a0 + bC0) - r0;
            float r1 = (m31 > 1.f) ? 1.f : 0.f; m31 = 0.9f * m31 + (a1 + bC1) - r1;
            float r2 = (m32 > 1.f) ? 1.f : 0.f; m32 = 0.9f * m32 + (a2 + bC2) - r2;
            float r3 = (m33 > 1.f) ? 1.f : 0.f; m33 = 0.9f * m33 + (a3 + bC3) - r3;
            if (s_ == 0) {
                float4 st;
                st.x = (m30 > 1.f) ? 1.f : 0.f;
                st.y = (m31 > 1.f) ? 1.f : 0.f;
                st.z = (m32 > 1.f) ? 1.f : 0.f;
                st.w = (m33 > 1.f) ? 1.f : 0.f;
                *reinterpret_cast<float4*>(&sspk3h[jb]) = st;
            }
        }
        __syncthreads();   // bar3: sspk3 ready

        // ===== phase D: fc2 (32->2) + LIF4 + count =====
        if (t2 < 64) {
            float v = sspk3h[t2 & 31] * wD;
            v += __shfl_xor(v, 16, 32);
            v += __shfl_xor(v, 8, 32);
            v += __shfl_xor(v, 4, 32);
            v += __shfl_xor(v, 2, 32);
            v += __shfl_xor(v, 1, 32);
            if ((t2 & 31) == 0) {
                float rr = (m4 > 1.f) ? 1.f : 0.f;
                m4 = 0.9f * m4 + (v + bD) - rr;
                if (m4 > 1.f) cnt += 1.f;
            }
        }
        // no barrier: next writer of sspk3 (phase C of t+1) is behind bar1+bar2
    }

    if (t2 == 0)  out[b * 2 + 0] = cnt;
    if (t2 == 32) out[b * 2 + 1] = cnt;
}

extern "C" void kernel_launch(void* const* d_in, const int* in_sizes, int n_in,
                              void* d_out, int out_size, void* d_ws, size_t ws_size,
                              hipStream_t stream) {
    const float* x   = (const float*)d_in[0];
    const float* w1  = (const float*)d_in[1];
    const float* b1  = (const float*)d_in[2];
    const float* w2  = (const float*)d_in[3];
    const float* b2  = (const float*)d_in[4];
    const float* wf1 = (const float*)d_in[5];
    const float* bf1 = (const float*)d_in[6];
    const float* wf2 = (const float*)d_in[7];
    const float* bf2 = (const float*)d_in[8];
    float* out = (float*)d_out;

    snn_all<<<NB / 2, 512, 0, stream>>>(x, w1, b1, w2, b2, wf1, bf1, wf2, bf2, out);
}